// Round 1
// baseline (485.325 us; speedup 1.0000x reference)
//
#include <hip/hip_runtime.h>
#include <hip/hip_bf16.h>
#include <stdint.h>
#include <stddef.h>

#define NB    64      // batch
#define NTOK  784
#define DIMC  256
#define NN2   4
#define NWS   7
#define NM    8
#define NHW   196
#define NC    32
#define NWIN  32      // windows per batch (n2*8+m)
#define NROWS 2048    // NB*NWIN
#define NK    392     // HW*D
#define NKP   448     // K padded to multiple of 64
#define NBIG  38416   // HW*HW
#define NPAD  38528   // N padded to 301*128
#define NTT   301     // N tiles of 128

typedef __attribute__((ext_vector_type(4))) float f32x4;
typedef __attribute__((ext_vector_type(2))) float f32x2;
typedef __attribute__((ext_vector_type(8))) short bf16x8;

static __device__ __forceinline__ float bf2f(unsigned short u) {
  union { unsigned int i; float f; } v; v.i = ((unsigned int)u) << 16; return v.f;
}
static __device__ __forceinline__ unsigned short f2bf(float f) {
  union { float f; unsigned int i; } v; v.f = f;
  unsigned int r = v.i + 0x7fffu + ((v.i >> 16) & 1u);  // RNE
  return (unsigned short)(r >> 16);
}

// ---------- kernel 1: compress (x@Wc+bc) + rearrange -> A bf16 [NROWS][NKP]
__global__ __launch_bounds__(256) void k_compress(
    const float* __restrict__ x, const float* __restrict__ Wc,
    const float* __restrict__ bc, unsigned short* __restrict__ Abf) {
  __shared__ float wcs[16 * 256];   // [md][c] transposed
  __shared__ float bcs[16];
  const int tid = threadIdx.x;
  const int b  = blockIdx.x / NN2;
  const int n2 = blockIdx.x % NN2;
  for (int idx = tid; idx < 4096; idx += 256) {
    int c = idx >> 4, md = idx & 15;
    wcs[md * 256 + c] = Wc[idx];
  }
  if (tid < 16) bcs[tid] = bc[tid];
  __syncthreads();
  if (tid < NHW) {
    const int h = tid / NWS, wcol = tid % NWS;
    const int t = h * 28 + n2 * 7 + wcol;
    const float* xp = x + ((size_t)b * NTOK + t) * DIMC;
    float acc[16];
    #pragma unroll
    for (int md = 0; md < 16; ++md) acc[md] = bcs[md];
    for (int c = 0; c < 256; c += 4) {
      const f32x4 xv = *(const f32x4*)(xp + c);
      #pragma unroll
      for (int md = 0; md < 16; ++md) {
        const f32x4 wv = *(const f32x4*)(wcs + md * 256 + c);
        acc[md] += xv[0]*wv[0] + xv[1]*wv[1] + xv[2]*wv[2] + xv[3]*wv[3];
      }
    }
    #pragma unroll
    for (int md = 0; md < 16; ++md) {
      const int m = md >> 1, d = md & 1;
      const int r = b * NWIN + n2 * NM + m;
      Abf[(size_t)r * NKP + tid * 2 + d] = f2bf(acc[md]);
    }
  }
  // zero the K pad [392,448)
  for (int e = tid; e < NM * (NKP - NK); e += 256) {
    const int m = e / (NKP - NK);
    const int k = NK + (e % (NKP - NK));
    const int r = b * NWIN + n2 * NM + m;
    Abf[(size_t)r * NKP + k] = 0;
  }
}

// ---------- kernel 2: Wg [NK][NBIG] f32 -> WgT [NPAD][NKP] bf16 (transpose+cast+pad)
__global__ __launch_bounds__(256) void k_wgt(
    const float* __restrict__ Wg, unsigned short* __restrict__ Wgbt) {
  __shared__ float tile[64][65];
  const int bid = blockIdx.x;
  const int n0 = (bid % 602) * 64;
  const int k0 = (bid / 602) * 64;
  const int tid = threadIdx.x;
  for (int idx = tid; idx < 4096; idx += 256) {
    const int kk = idx >> 6, nn = idx & 63;
    const int k = k0 + kk, n = n0 + nn;
    tile[nn][kk] = (k < NK && n < NBIG) ? Wg[(size_t)k * NBIG + n] : 0.f;
  }
  __syncthreads();
  for (int idx = tid; idx < 4096; idx += 256) {
    const int nn = idx >> 6, kk = idx & 63;
    Wgbt[(size_t)(n0 + nn) * NKP + (k0 + kk)] = f2bf(tile[nn][kk]);
  }
}

// ---------- kernel 3: S[rc][NPAD] bf16 = A[rc][NKP] @ WgT^T + bg   (m97-style MFMA GEMM)
__global__ __launch_bounds__(256) void k_gemm(
    const unsigned short* __restrict__ A,   // chunk base
    const unsigned short* __restrict__ Bt,  // [NPAD][NKP]
    const float* __restrict__ bg,
    unsigned short* __restrict__ S) {       // [rc][NPAD]
  __shared__ __align__(128) short As[128 * 64];
  __shared__ __align__(128) short Bs[128 * 64];
  const int tid = threadIdx.x;
  const int w = tid >> 6, lane = tid & 63;
  const int mt = blockIdx.x / NTT, nt = blockIdx.x % NTT;
  const int m0 = mt * 128, n0 = nt * 128;
  const int wm = (w >> 1) * 64, wn = (w & 1) * 64;
  const int lrow = lane >> 3, lcol = (lane & 7) * 8;
  f32x4 acc[4][4] = {};
  for (int kt = 0; kt < NKP; kt += 64) {
    #pragma unroll
    for (int is = 0; is < 4; ++is) {
      const int gg = w * 4 + is;
      const int row = gg * 8 + lrow;
      const unsigned short* ga = A  + (size_t)(m0 + row) * NKP + kt + lcol;
      const unsigned short* gb = Bt + (size_t)(n0 + row) * NKP + kt + lcol;
      __builtin_amdgcn_global_load_lds(
          (const __attribute__((address_space(1))) void*)ga,
          (__attribute__((address_space(3))) void*)((char*)As + gg * 1024), 16, 0, 0);
      __builtin_amdgcn_global_load_lds(
          (const __attribute__((address_space(1))) void*)gb,
          (__attribute__((address_space(3))) void*)((char*)Bs + gg * 1024), 16, 0, 0);
    }
    __syncthreads();
    #pragma unroll
    for (int kk = 0; kk < 2; ++kk) {
      bf16x8 af[4], bfr[4];
      #pragma unroll
      for (int i = 0; i < 4; ++i) {
        af[i]  = *(const bf16x8*)(As + (wm + i * 16 + (lane & 15)) * 64 + kk * 32 + (lane >> 4) * 8);
        bfr[i] = *(const bf16x8*)(Bs + (wn + i * 16 + (lane & 15)) * 64 + kk * 32 + (lane >> 4) * 8);
      }
      #pragma unroll
      for (int mi = 0; mi < 4; ++mi)
        #pragma unroll
        for (int ni = 0; ni < 4; ++ni)
          acc[mi][ni] = __builtin_amdgcn_mfma_f32_16x16x32_bf16(af[mi], bfr[ni], acc[mi][ni], 0, 0, 0);
    }
    __syncthreads();
  }
  #pragma unroll
  for (int ni = 0; ni < 4; ++ni) {
    const int col = n0 + wn + ni * 16 + (lane & 15);
    const float bgv = (col < NBIG) ? bg[col] : 0.f;
    #pragma unroll
    for (int mi = 0; mi < 4; ++mi) {
      #pragma unroll
      for (int e = 0; e < 4; ++e) {
        const int row = m0 + wm + mi * 16 + (lane >> 4) * 4 + e;
        S[(size_t)row * NPAD + col] = f2bf(acc[mi][ni][e] + bgv);
      }
    }
  }
}

// ---------- kernel 4: per-(b,window) column softmax + mixing matmul + scatter
__global__ __launch_bounds__(256) void k_softmax_mix(
    const unsigned short* __restrict__ S,  // chunk base [rc][NPAD]
    const float* __restrict__ x,
    float* __restrict__ out, int row0) {
  __shared__ float xv[NHW * NC];       // [i][c]
  __shared__ float P[NHW * 64];        // [i][j] current j-chunk
  __shared__ float pmax[4 * 64], psum[4 * 64], colinv[64];
  const int tid = threadIdx.x;
  const int r = row0 + blockIdx.x;
  const int b = r >> 5, win = r & 31, n2 = win >> 3, m = win & 7;
  for (int idx = tid; idx < NHW * 8; idx += 256) {
    const int i = idx >> 3, c4 = (idx & 7) * 4;
    const int h = i / NWS, wcol = i % NWS;
    const int t = h * 28 + n2 * 7 + wcol;
    *(f32x4*)(xv + i * NC + c4) =
        *(const f32x4*)(x + ((size_t)b * NTOK + t) * DIMC + m * NC + c4);
  }
  const unsigned short* Srow = S + (size_t)blockIdx.x * NPAD;
  const int sg = tid >> 6, sj = tid & 63;
  for (int j0 = 0; j0 < NHW; j0 += 64) {
    __syncthreads();  // protect P/colinv from previous chunk's readers
    for (int idx = tid; idx < NHW * 32; idx += 256) {
      const int i = idx >> 5, jp = (idx & 31) * 2;
      const unsigned int vv = *(const unsigned int*)(Srow + i * NHW + j0 + jp);
      f32x2 pv = { bf2f((unsigned short)(vv & 0xffffu)),
                   bf2f((unsigned short)(vv >> 16)) };
      *(f32x2*)(P + i * 64 + jp) = pv;
    }
    __syncthreads();
    const int ibeg = sg * 49, iend = ibeg + 49;
    float mx = -3.0e38f;
    for (int i = ibeg; i < iend; ++i) mx = fmaxf(mx, P[i * 64 + sj]);
    pmax[sg * 64 + sj] = mx;
    __syncthreads();
    const float cm = fmaxf(fmaxf(pmax[sj], pmax[64 + sj]),
                           fmaxf(pmax[128 + sj], pmax[192 + sj]));
    float sum = 0.f;
    for (int i = ibeg; i < iend; ++i) {
      const float e = __expf(P[i * 64 + sj] - cm);
      P[i * 64 + sj] = e;
      sum += e;
    }
    psum[sg * 64 + sj] = sum;
    __syncthreads();
    if (sg == 0)
      colinv[sj] = 1.f / (psum[sj] + psum[64 + sj] + psum[128 + sj] + psum[192 + sj]);
    __syncthreads();
    // mix: thread = (cg=sg -> c0=8*sg, j = j0+sj); xv reads are wave-uniform broadcasts
    float a0=0,a1=0,a2=0,a3=0,a4=0,a5=0,a6=0,a7=0;
    const int c0 = sg * 8;
    #pragma unroll 2
    for (int i = 0; i < NHW; ++i) {
      const float p = P[i * 64 + sj];
      const f32x4 xa = *(const f32x4*)(xv + i * NC + c0);
      const f32x4 xb = *(const f32x4*)(xv + i * NC + c0 + 4);
      a0 += p * xa[0]; a1 += p * xa[1]; a2 += p * xa[2]; a3 += p * xa[3];
      a4 += p * xb[0]; a5 += p * xb[1]; a6 += p * xb[2]; a7 += p * xb[3];
    }
    const int j = j0 + sj;
    if (j < NHW) {
      const float sc = colinv[sj];
      const int h2 = j / NWS, w2 = j % NWS;
      const int t2 = h2 * 28 + n2 * 7 + w2;
      float* op = out + ((size_t)b * NTOK + t2) * DIMC + m * NC + c0;
      f32x4 o0 = { a0*sc, a1*sc, a2*sc, a3*sc };
      f32x4 o1 = { a4*sc, a5*sc, a6*sc, a7*sc };
      *(f32x4*)op = o0;
      *(f32x4*)(op + 4) = o1;
    }
  }
}

extern "C" void kernel_launch(void* const* d_in, const int* in_sizes, int n_in,
                              void* d_out, int out_size, void* d_ws, size_t ws_size,
                              hipStream_t stream) {
  const float* x  = (const float*)d_in[0];
  const float* Wc = (const float*)d_in[1];
  const float* bc = (const float*)d_in[2];
  const float* Wg = (const float*)d_in[3];
  const float* bg = (const float*)d_in[4];
  float* out = (float*)d_out;

  char* ws = (char*)d_ws;
  const size_t wgbt_bytes = (size_t)NPAD * NKP * 2;   // 34.5 MB
  const size_t a_bytes    = (size_t)NROWS * NKP * 2;  // 1.8 MB
  unsigned short* Wgbt = (unsigned short*)ws;
  unsigned short* Abf  = (unsigned short*)(ws + wgbt_bytes);
  unsigned short* S    = (unsigned short*)(ws + wgbt_bytes + a_bytes);
  const size_t srow_bytes = (size_t)NPAD * 2;

  size_t avail = (ws_size > wgbt_bytes + a_bytes) ? (ws_size - wgbt_bytes - a_bytes) : 0;
  int rows_chunk = (int)(avail / srow_bytes);
  rows_chunk = (rows_chunk / 128) * 128;
  if (rows_chunk > NROWS) rows_chunk = NROWS;
  if (rows_chunk < 128)  rows_chunk = 128;   // minimum viable; needs ~46 MB ws

  hipLaunchKernelGGL(k_compress, dim3(NB * NN2), dim3(256), 0, stream, x, Wc, bc, Abf);
  hipLaunchKernelGGL(k_wgt, dim3(602 * 7), dim3(256), 0, stream, Wg, Wgbt);
  for (int row0 = 0; row0 < NROWS; row0 += rows_chunk) {
    int rc = NROWS - row0; if (rc > rows_chunk) rc = rows_chunk;
    hipLaunchKernelGGL(k_gemm, dim3((rc / 128) * NTT), dim3(256), 0, stream,
                       Abf + (size_t)row0 * NKP, Wgbt, bg, S);
    hipLaunchKernelGGL(k_softmax_mix, dim3(rc), dim3(256), 0, stream, S, x, out, row0);
  }
}